// Round 20
// baseline (287.339 us; speedup 1.0000x reference)
//
#include <hip/hip_runtime.h>
#include <stdint.h>
#include <float.h>

// x[4096,256] f32, keys[65536,256] f32, values[65536,10] f32, k=8 (hardcoded).
#define B_ROWS 4096
#define N_KEYS 65536
#define DDIM 256
#define NCH 10

#define NSPLIT 16
#define SPLIT_KEYS (N_KEYS / NSPLIT)       // 4096
#define ROWS_PER_BLK 128
#define CHUNK_KEYS 32
#define NCHUNK (SPLIT_KEYS / CHUNK_KEYS)   // 128

typedef float f32x4 __attribute__((ext_vector_type(4)));
typedef short bf16x8 __attribute__((ext_vector_type(8)));

static __device__ __forceinline__ unsigned short f2bf(float f) {
  unsigned u = __float_as_uint(f);
  return (unsigned short)((u + 0x7FFFu + ((u >> 16) & 1u)) >> 16);
}
static __device__ __forceinline__ unsigned ford(float f) {
  unsigned u = __float_as_uint(f);
  return u ^ ((unsigned)((int)u >> 31) | 0x80000000u);
}
static __device__ __forceinline__ unsigned long long shfl_xor_u64(unsigned long long v, int m) {
  unsigned lo = __shfl_xor((unsigned)v, m, 64);
  unsigned hi = __shfl_xor((unsigned)(v >> 32), m, 64);
  return ((unsigned long long)hi << 32) | lo;
}
static __device__ __forceinline__ double shfl_xor_f64(double v, int m) {
  return __longlong_as_double((long long)shfl_xor_u64((unsigned long long)__double_as_longlong(v), m));
}
static __device__ __forceinline__ void gl_lds16(const void* g, void* l) {
  __builtin_amdgcn_global_load_lds(
      (const __attribute__((address_space(1))) unsigned int*)g,
      (__attribute__((address_space(3))) unsigned int*)l, 16, 0, 0);
}

// ---------------------------------------------------------------------------
// transpose_keys: bf16-convert + transpose + fused ksq. Output: per 32-key
// record [koct 0..31][key 0..31][16B] (16KB): knn_main staging is a LINEAR
// copy; A-frag ds_read_b128s are 256B-contiguous per 16-lane phase.
// ---------------------------------------------------------------------------
__global__ __launch_bounds__(256) void transpose_keys(const float* __restrict__ keys,
                                                      unsigned char* __restrict__ kbf,
                                                      float* __restrict__ ksq) {
  __shared__ __align__(16) unsigned char T[128 * 512];
  const int t = threadIdx.x;
  const int lane = t & 63;
  const float4* src = (const float4*)(keys + (size_t)blockIdx.x * 128 * DDIM);
#pragma unroll
  for (int j = 0; j < 32; ++j) {
    int g = j * 256 + t;
    float4 v = src[g];
    int key = g >> 6;
    int u = lane >> 1, sub = lane & 1;
    unsigned lo = ((unsigned)f2bf(v.y) << 16) | f2bf(v.x);
    unsigned hi2 = ((unsigned)f2bf(v.w) << 16) | f2bf(v.z);
    unsigned long long p = ((unsigned long long)hi2 << 32) | lo;
    *(unsigned long long*)&T[key * 512 + ((u ^ (key & 7)) << 4) + (sub << 3)] = p;
    float ss = v.x * v.x + v.y * v.y + v.z * v.z + v.w * v.w;
#pragma unroll
    for (int off = 32; off; off >>= 1) ss += __shfl_xor(ss, off, 64);
    if (lane == 0) ksq[blockIdx.x * 128 + key] = ss;
  }
  __syncthreads();
  uint4* dst = (uint4*)kbf + (size_t)blockIdx.x * 4096; // 4 records of 1024 units
#pragma unroll
  for (int j = 0; j < 16; ++j) {
    int ou = j * 256 + t;                 // rec(4) x koct(32) x key32(32)
    int rec = ou >> 10, rem = ou & 1023;
    int koct = rem >> 5, key32 = rem & 31;
    int keyl = rec * 32 + key32;
    dst[ou] = *(const uint4*)&T[keyl * 512 + ((koct ^ (keyl & 7)) << 4)];
  }
}

// ---------------------------------------------------------------------------
// knn_main (champion ring-4 + 2-CHUNKS-PER-BARRIER):
// 512 thr = 8 waves = 2 key-halves (mw, 16 keys) x 4 row-groups (ws, 32 rows
// = 2 reg sets, feed-2). Block: 128 rows x one 4096-key split, 64 periods of
// 2x32-key chunks. 2 blocks/CU. Period p: compute chunks 2p,2p+1 from bufs
// (2p)&3,(2p+1)&3; stage 2p+2,2p+3 into the OTHER two buffers (last read in
// period p-1; every wave is past this period's barrier => no reader left).
// Entry wait vmcnt(2): the 2 LOADQs are pinned AFTER the STAGEs via
// sched_barrier(0), so <=2 outstanding => all 4 staging gl_lds retired
// (in-order retirement; rare SEL pool-stores are newer => only makes the
// wait conservative). Barriers/waits per block: 128 -> 64; RDTAU/PUBLISH
// amortized; COMPUTE(c1) overlaps SEL(c0) (independent accumulators).
// ksq folded into MFMA C-init (x pre-scaled by -2): scores = accumulator.
// Selection: tau filter + append (8 streams/row = hi(4) x mw(2); tau_row =
// max of 8 stream minima >= true 8th-best; overflow -> per-split exact
// rescan in refine, correctness unconditional).
// ---------------------------------------------------------------------------
__global__ __launch_bounds__(512, 4) void knn_main(
    const float* __restrict__ x,
    const unsigned char* __restrict__ kbf,
    const float* __restrict__ ksqg,
    unsigned int* __restrict__ pools,
    unsigned int* __restrict__ counts,
    int CAP) {
  __shared__ __align__(16) unsigned char tiles[4][16384]; // 64KB ring
  __shared__ float tauh[2][4][16][2]; // [set][ws][lo4][mw]; monotone
  __shared__ unsigned int rowcnt[128];

  const int t = threadIdx.x;
  const int lane = t & 63;
  const int wv = t >> 6;          // 0..7
  const int mw = wv & 1;          // key half (16 keys)
  const int ws = wv >> 1;         // row group (32 rows)
  const int lo4 = lane & 15;
  const int hi = lane >> 4;

  const int split = blockIdx.x & (NSPLIT - 1);
  const int rb = (blockIdx.x >> 4) * ROWS_PER_BLK;
  const int sb = split * SPLIT_KEYS;

  const int xrow0 = rb + ws * 32 + lo4;
  const int xrow1 = xrow0 + 16;
  const int rl0 = ws * 32 + lo4, rl1 = rl0 + 16;

  // ---- x fragments PRE-SCALED by -2 (folds the -2 into the MFMA)
  bf16x8 xb0[8], xb1[8];
#pragma unroll
  for (int s = 0; s < 8; ++s) {
    const float* p0 = x + (size_t)xrow0 * DDIM + s * 32 + hi * 8;
    const float* p1 = x + (size_t)xrow1 * DDIM + s * 32 + hi * 8;
    float4 a = *(const float4*)p0, b = *(const float4*)(p0 + 4);
    float4 c = *(const float4*)p1, d = *(const float4*)(p1 + 4);
    union { unsigned short us[8]; bf16x8 v; } u0, u1;
    u0.us[0]=f2bf(-2.f*a.x); u0.us[1]=f2bf(-2.f*a.y); u0.us[2]=f2bf(-2.f*a.z); u0.us[3]=f2bf(-2.f*a.w);
    u0.us[4]=f2bf(-2.f*b.x); u0.us[5]=f2bf(-2.f*b.y); u0.us[6]=f2bf(-2.f*b.z); u0.us[7]=f2bf(-2.f*b.w);
    u1.us[0]=f2bf(-2.f*c.x); u1.us[1]=f2bf(-2.f*c.y); u1.us[2]=f2bf(-2.f*c.z); u1.us[3]=f2bf(-2.f*c.w);
    u1.us[4]=f2bf(-2.f*d.x); u1.us[5]=f2bf(-2.f*d.y); u1.us[6]=f2bf(-2.f*d.z); u1.us[7]=f2bf(-2.f*d.w);
    xb0[s] = u0.v; xb1[s] = u1.v;
  }

  if (t < 128) rowcnt[t] = 0;

  float smin0 = FLT_MAX, smin1 = FLT_MAX;
  const unsigned char* srcbase = kbf + ((size_t)(split * NCHUNK) << 14);
  const size_t pb0 = ((size_t)xrow0 * NSPLIT + split) * (size_t)CAP;
  const size_t pb1 = ((size_t)xrow1 * NSPLIT + split) * (size_t)CAP;

  auto STAGE = [&](int c, int buf) { // linear 16KB, 2 x 16B per thread
    const unsigned char* src = srcbase + ((size_t)c << 14);
#pragma unroll
    for (int i = 0; i < 2; ++i)
      gl_lds16(src + (((i * 512) + t) << 4),
               (unsigned char*)tiles[buf] + ((i * 512 + wv * 64) << 4));
  };
  auto LOADQ = [&](int c) {
    return *(const float4*)(ksqg + sb + c * CHUNK_KEYS + mw * 16 + hi * 4);
  };

  f32x4 a0, a1;

  auto COMPUTE = [&](int buf, float4 kq) { // acc init = ksq (fold), then MFMA
    const unsigned char* tile = tiles[buf];
    f32x4 ini;
    ini[0] = kq.x; ini[1] = kq.y; ini[2] = kq.z; ini[3] = kq.w;
    a0 = ini; a1 = ini;
    __builtin_amdgcn_s_setprio(1);
#pragma unroll
    for (int s = 0; s < 8; ++s) {
      const unsigned char* rp = tile + (s * 4 + hi) * 512 + (mw * 16 + lo4) * 16;
      bf16x8 af = *(const bf16x8*)rp;
      a0 = __builtin_amdgcn_mfma_f32_16x16x32_bf16(af, xb0[s], a0, 0, 0, 0);
      a1 = __builtin_amdgcn_mfma_f32_16x16x32_bf16(af, xb1[s], a1, 0, 0, 0);
    }
    __builtin_amdgcn_s_setprio(0);
  };

  auto SEL = [&](int c, bool append, float tau0, float tau1) {
    float mb0 = fminf(fminf(a0[0], a0[1]), fminf(a0[2], a0[3]));
    float mb1 = fminf(fminf(a1[0], a1[1]), fminf(a1[2], a1[3]));
    smin0 = fminf(smin0, mb0);
    smin1 = fminf(smin1, mb1);
    if (append) {
      const int kloc = c * CHUNK_KEYS + mw * 16 + hi * 4; // 12-bit local idx
      if (mb0 <= tau0) { // rare
#pragma unroll
        for (int i = 0; i < 4; ++i) {
          if (a0[i] <= tau0) {
            unsigned slot = atomicAdd(&rowcnt[rl0], 1u);
            if ((int)slot < CAP)
              pools[pb0 + slot] = (ford(a0[i]) & 0xFFFFF000u) | (unsigned)(kloc + i);
          }
        }
      }
      if (mb1 <= tau1) {
#pragma unroll
        for (int i = 0; i < 4; ++i) {
          if (a1[i] <= tau1) {
            unsigned slot = atomicAdd(&rowcnt[rl1], 1u);
            if ((int)slot < CAP)
              pools[pb1 + slot] = (ford(a1[i]) & 0xFFFFF000u) | (unsigned)(kloc + i);
          }
        }
      }
    }
  };

  auto RDTAU = [&](float& tau0, float& tau1) { // max over both mw entries
    tau0 = fmaxf(tauh[0][ws][lo4][0], tauh[0][ws][lo4][1]);
    tau1 = fmaxf(tauh[1][ws][lo4][0], tauh[1][ws][lo4][1]);
  };

  auto PUBLISH = [&]() { // per wave: max over its 4 hi-stream minima
    float p0 = fmaxf(smin0, __shfl_xor(smin0, 16, 64));
    p0 = fmaxf(p0, __shfl_xor(p0, 32, 64));
    float p1 = fmaxf(smin1, __shfl_xor(smin1, 16, 64));
    p1 = fmaxf(p1, __shfl_xor(p1, 32, 64));
    if (hi == 0) {
      tauh[0][ws][lo4][mw] = p0;
      tauh[1][ws][lo4][mw] = p1;
    }
  };

  // ---- prologue: tau from chunks 0 and 64 (minima only)
  STAGE(0, 0);
  STAGE(64, 1);
  __syncthreads();               // full drain (prologue only)
  {
    float4 q = LOADQ(0);
    COMPUTE(0, q); SEL(0, false, 0.f, 0.f);
    q = LOADQ(64);
    COMPUTE(1, q); SEL(64, false, 0.f, 0.f);
  }
  PUBLISH();
  __syncthreads();               // tauh visible; prologue reads done

  // prime: chunk 0 still valid in buf 0; stage chunk 1 over buf 1
  STAGE(1, 1);
  __builtin_amdgcn_sched_barrier(0); // keep LQs AFTER the staging gl_lds
  float4 kqc0 = LOADQ(0);
  float4 kqc1 = LOADQ(1);
  float4 kqn0, kqn1;

#pragma unroll 1
  for (int p = 0; p < NCHUNK / 2; ++p) {
    const int c0 = 2 * p, c1 = c0 + 1;
    // <=2 outstanding => all older staging gl_lds retired (LQs are newer)
    asm volatile("s_waitcnt vmcnt(2)" ::: "memory");
    __builtin_amdgcn_s_barrier();
    const int n0 = (c0 + 2 < NCHUNK) ? c0 + 2 : 0; // tail: dummy re-stage
    const int n1 = (c1 + 2 < NCHUNK) ? c1 + 2 : 1;
    STAGE(n0, (c0 + 2) & 3);     // bufs not read this period; readers of
    STAGE(n1, (c1 + 2) & 3);     // period p-1 are all past this barrier
    __builtin_amdgcn_sched_barrier(0); // pin: LQs issue after staging
    kqn0 = LOADQ(n0);
    kqn1 = LOADQ(n1);
    float tau0, tau1;
    RDTAU(tau0, tau1);           // lagged/racy tau: always a valid upper bound
    COMPUTE(c0 & 3, kqc0);
    SEL(c0, true, tau0, tau1);
    COMPUTE(c1 & 3, kqc1);
    SEL(c1, true, tau0, tau1);
    PUBLISH();
    kqc0 = kqn0; kqc1 = kqn1;
  }

  __syncthreads();
  if (t < 128) counts[(size_t)(rb + t) * NSPLIT + split] = rowcnt[t];
}

// ---------------------------------------------------------------------------
// knn_refine: per row (1 wave): scan the row's 16 pools (overflowed split ->
// exact fp32 rescan of THAT 4096-key split), tournament top-24 by quantized
// score, fp64-exact recompute, true top-8 (idx tiebreak), average values.
// ---------------------------------------------------------------------------
__global__ __launch_bounds__(64) void knn_refine(
    const float* __restrict__ x,
    const float* __restrict__ keys,
    const float* __restrict__ ksq,
    const float* __restrict__ values,
    const unsigned int* __restrict__ pools,
    const unsigned int* __restrict__ counts,
    int CAP,
    float* __restrict__ out) {
  __shared__ float4 xl[64];
  const int row = blockIdx.x;
  const int lane = threadIdx.x;

  xl[lane] = ((const float4*)(x + (size_t)row * DDIM))[lane];
  __syncthreads();

  unsigned long long h[8];
#pragma unroll
  for (int i = 0; i < 8; ++i) h[i] = ~0ULL;

  auto insert = [&](unsigned long long v) {
    if (v < h[7]) {
#pragma unroll
      for (int j = 7; j >= 1; --j) {
        unsigned long long a = h[j - 1];
        unsigned long long mx = a > v ? a : v;
        h[j] = (v < h[j]) ? mx : h[j];
      }
      h[0] = h[0] < v ? h[0] : v;
    }
  };

  for (int s = 0; s < NSPLIT; ++s) {
    unsigned cnt = counts[(size_t)row * NSPLIT + s];
    if ((int)cnt <= CAP) {
      const unsigned int* pp = pools + ((size_t)row * NSPLIT + s) * (size_t)CAP;
      for (int i = lane; i < (int)cnt; i += 64) {
        unsigned p = pp[i];
        unsigned gk = (unsigned)(s * SPLIT_KEYS) + (p & 0xFFFu);
        insert(((unsigned long long)(p & 0xFFFFF000u) << 16) | gk);
      }
    } else {
      // overflow fallback: exact fp32 rescan of this 4096-key split
      for (int kk = lane; kk < SPLIT_KEYS; kk += 64) {
        int gk = s * SPLIT_KEYS + kk;
        const float4* kr = (const float4*)(keys + (size_t)gk * DDIM);
        float acc = 0.f;
#pragma unroll 8
        for (int d = 0; d < 64; ++d) {
          float4 kv = kr[d], xv = xl[d];
          acc = fmaf(kv.x, xv.x, acc); acc = fmaf(kv.y, xv.y, acc);
          acc = fmaf(kv.z, xv.z, acc); acc = fmaf(kv.w, xv.w, acc);
        }
        float sc = fmaf(-2.0f, acc, ksq[gk]);
        insert(((unsigned long long)(ford(sc) & 0xFFFFF000u) << 16) | (unsigned)gk);
      }
    }
  }

  // ---- tournament: top-24 by quantized score (u64 unique: gk in low 16b)
  int myidx = 0;
#pragma unroll 1
  for (int r = 0; r < 24; ++r) {
    unsigned long long m = h[0];
#pragma unroll
    for (int off = 32; off; off >>= 1) {
      unsigned long long o = shfl_xor_u64(m, off);
      m = o < m ? o : m;
    }
    if (lane == r) myidx = (int)(m & 0xFFFFu);
    if (h[0] == m) {
#pragma unroll
      for (int i = 0; i < 7; ++i) h[i] = h[i + 1];
      h[7] = ~0ULL;
    }
  }

  // ---- exact fp64 distance for my candidate
  double dv = 1e300;
  if (lane < 24) {
    const float4* kr = (const float4*)(keys + (size_t)myidx * DDIM);
    double s = 0.0;
#pragma unroll 8
    for (int d = 0; d < 64; ++d) {
      float4 kv = kr[d], xv = xl[d];
      double d0 = (double)xv.x - (double)kv.x;
      double d1 = (double)xv.y - (double)kv.y;
      double d2 = (double)xv.z - (double)kv.z;
      double d3 = (double)xv.w - (double)kv.w;
      s += d0 * d0 + d1 * d1 + d2 * d2 + d3 * d3;
    }
    dv = s;
  }

  int di = myidx;
  int chosen[8];
#pragma unroll
  for (int r = 0; r < 8; ++r) {
    double m = dv; int mi = di;
#pragma unroll
    for (int off = 32; off; off >>= 1) {
      double om = shfl_xor_f64(m, off);
      int omi = __shfl_xor(mi, off, 64);
      if (om < m || (om == m && omi < mi)) { m = om; mi = omi; }
    }
    chosen[r] = mi;
    if (di == mi && dv < 1e300) dv = 1e300;
  }

  if (lane < NCH) {
    double a = 0.0;
#pragma unroll
    for (int r = 0; r < 8; ++r) a += (double)values[(size_t)chosen[r] * NCH + lane];
    out[row * NCH + lane] = (float)(a * 0.125);
  }
}

// ---------------------------------------------------------------------------
extern "C" void kernel_launch(void* const* d_in, const int* in_sizes, int n_in,
                              void* d_out, int out_size, void* d_ws, size_t ws_size,
                              hipStream_t stream) {
  (void)in_sizes; (void)n_in; (void)out_size;
  const float* x      = (const float*)d_in[0];
  const float* keys   = (const float*)d_in[1];
  const float* values = (const float*)d_in[2];
  float* out = (float*)d_out;

  char* ws = (char*)d_ws;
  unsigned char* kbf = (unsigned char*)ws;                            // 32 MB transposed bf16 keys
  float* ksq   = (float*)(ws + 33554432);                             // 256 KB
  unsigned int* counts = (unsigned int*)(ws + 33554432 + 262144);     // 256 KB (4096x16)
  unsigned int* pools  = (unsigned int*)(ws + 33554432 + 262144 + 262144);

  size_t base = 33554432 + 262144 + 262144;
  size_t cap = (ws_size > base) ? (ws_size - base) / ((size_t)B_ROWS * NSPLIT * 4) : 60;
  if (cap < 60) cap = 60;      // 60 -> pool ends <49.8 MB (< proven 50.6)
  if (cap > 512) cap = 512;
  int CAP = (int)cap;

  transpose_keys<<<N_KEYS / 128, 256, 0, stream>>>(keys, kbf, ksq);
  knn_main<<<(B_ROWS / ROWS_PER_BLK) * NSPLIT, 512, 0, stream>>>(
      x, kbf, ksq, pools, counts, CAP);
  knn_refine<<<B_ROWS, 64, 0, stream>>>(x, keys, ksq, values, pools, counts, CAP, out);
}

// Round 21
// 276.285 us; speedup vs baseline: 1.0400x; 1.0400x over previous
//
#include <hip/hip_runtime.h>
#include <stdint.h>
#include <float.h>

// x[4096,256] f32, keys[65536,256] f32, values[65536,10] f32, k=8 (hardcoded).
#define B_ROWS 4096
#define N_KEYS 65536
#define DDIM 256
#define NCH 10

#define NSPLIT 16
#define SPLIT_KEYS (N_KEYS / NSPLIT)       // 4096
#define ROWS_PER_BLK 128
#define CHUNK_KEYS 32
#define NCHUNK (SPLIT_KEYS / CHUNK_KEYS)   // 128

typedef float f32x4 __attribute__((ext_vector_type(4)));
typedef short bf16x8 __attribute__((ext_vector_type(8)));

static __device__ __forceinline__ unsigned short f2bf(float f) {
  unsigned u = __float_as_uint(f);
  return (unsigned short)((u + 0x7FFFu + ((u >> 16) & 1u)) >> 16);
}
static __device__ __forceinline__ unsigned ford(float f) {
  unsigned u = __float_as_uint(f);
  return u ^ ((unsigned)((int)u >> 31) | 0x80000000u);
}
static __device__ __forceinline__ unsigned long long shfl_xor_u64(unsigned long long v, int m) {
  unsigned lo = __shfl_xor((unsigned)v, m, 64);
  unsigned hi = __shfl_xor((unsigned)(v >> 32), m, 64);
  return ((unsigned long long)hi << 32) | lo;
}
static __device__ __forceinline__ double shfl_xor_f64(double v, int m) {
  return __longlong_as_double((long long)shfl_xor_u64((unsigned long long)__double_as_longlong(v), m));
}
static __device__ __forceinline__ void gl_lds16(const void* g, void* l) {
  __builtin_amdgcn_global_load_lds(
      (const __attribute__((address_space(1))) unsigned int*)g,
      (__attribute__((address_space(3))) unsigned int*)l, 16, 0, 0);
}

// ---------------------------------------------------------------------------
// transpose_keys: bf16-convert + transpose + fused ksq. Output: per 32-key
// record [koct 0..31][key 0..31][16B] (16KB): knn_main staging is a LINEAR
// copy; A-frag ds_read_b128s are 256B-contiguous per 16-lane phase.
// ---------------------------------------------------------------------------
__global__ __launch_bounds__(256) void transpose_keys(const float* __restrict__ keys,
                                                      unsigned char* __restrict__ kbf,
                                                      float* __restrict__ ksq) {
  __shared__ __align__(16) unsigned char T[128 * 512];
  const int t = threadIdx.x;
  const int lane = t & 63;
  const float4* src = (const float4*)(keys + (size_t)blockIdx.x * 128 * DDIM);
#pragma unroll
  for (int j = 0; j < 32; ++j) {
    int g = j * 256 + t;
    float4 v = src[g];
    int key = g >> 6;
    int u = lane >> 1, sub = lane & 1;
    unsigned lo = ((unsigned)f2bf(v.y) << 16) | f2bf(v.x);
    unsigned hi2 = ((unsigned)f2bf(v.w) << 16) | f2bf(v.z);
    unsigned long long p = ((unsigned long long)hi2 << 32) | lo;
    *(unsigned long long*)&T[key * 512 + ((u ^ (key & 7)) << 4) + (sub << 3)] = p;
    float ss = v.x * v.x + v.y * v.y + v.z * v.z + v.w * v.w;
#pragma unroll
    for (int off = 32; off; off >>= 1) ss += __shfl_xor(ss, off, 64);
    if (lane == 0) ksq[blockIdx.x * 128 + key] = ss;
  }
  __syncthreads();
  uint4* dst = (uint4*)kbf + (size_t)blockIdx.x * 4096; // 4 records of 1024 units
#pragma unroll
  for (int j = 0; j < 16; ++j) {
    int ou = j * 256 + t;                 // rec(4) x koct(32) x key32(32)
    int rec = ou >> 10, rem = ou & 1023;
    int koct = rem >> 5, key32 = rem & 31;
    int keyl = rec * 32 + key32;
    dst[ou] = *(const uint4*)&T[keyl * 512 + ((koct ^ (keyl & 7)) << 4)];
  }
}

// ---------------------------------------------------------------------------
// knn_main (champion: convoy + T3/T4 counted-vmcnt 4-buffer ring + 2x row
// amortization): 512 thr = 8 waves = 2 key-halves (mw, 16 keys) x 4 row-
// groups (ws, 32 rows = 2 reg sets, feed-2). Block: 128 rows x one 4096-key
// split in 128 chunks of 32 keys. 2 blocks/CU (unified-VGPR-capped 16
// waves/CU). 4-buffer LDS ring with lookahead-2: per chunk ONE raw s_barrier
// preceded by s_waitcnt vmcnt(4) — the next 2 chunks' staging loads stay IN
// FLIGHT across the barrier (never drains; pool atomics only make the wait
// conservative, never unsafe). Ring safety: STAGE(c+3) overwrites
// buf((c-1)&3), last read in period c-1; any wave past period-c's barrier
// has executed its period-(c-1) MFMAs, so no reader remains.
// ksq folded into MFMA C-init (x pre-scaled by -2): scores = accumulator.
// Selection: tau filter + append (8 streams/row = hi(4) x mw(2); tau_row =
// max of 8 stream minima >= true 8th-best; overflow -> per-split exact
// rescan in refine, correctness unconditional).
// ---------------------------------------------------------------------------
__global__ __launch_bounds__(512, 4) void knn_main(
    const float* __restrict__ x,
    const unsigned char* __restrict__ kbf,
    const float* __restrict__ ksqg,
    unsigned int* __restrict__ pools,
    unsigned int* __restrict__ counts,
    int CAP) {
  __shared__ __align__(16) unsigned char tiles[4][16384]; // 64KB ring
  __shared__ float tauh[2][4][16][2]; // [set][ws][lo4][mw]; monotone
  __shared__ unsigned int rowcnt[128];

  const int t = threadIdx.x;
  const int lane = t & 63;
  const int wv = t >> 6;          // 0..7
  const int mw = wv & 1;          // key half (16 keys)
  const int ws = wv >> 1;         // row group (32 rows)
  const int lo4 = lane & 15;
  const int hi = lane >> 4;

  const int split = blockIdx.x & (NSPLIT - 1);
  const int rb = (blockIdx.x >> 4) * ROWS_PER_BLK;
  const int sb = split * SPLIT_KEYS;

  const int xrow0 = rb + ws * 32 + lo4;
  const int xrow1 = xrow0 + 16;
  const int rl0 = ws * 32 + lo4, rl1 = rl0 + 16;

  // ---- x fragments PRE-SCALED by -2 (folds the -2 into the MFMA)
  bf16x8 xb0[8], xb1[8];
#pragma unroll
  for (int s = 0; s < 8; ++s) {
    const float* p0 = x + (size_t)xrow0 * DDIM + s * 32 + hi * 8;
    const float* p1 = x + (size_t)xrow1 * DDIM + s * 32 + hi * 8;
    float4 a = *(const float4*)p0, b = *(const float4*)(p0 + 4);
    float4 c = *(const float4*)p1, d = *(const float4*)(p1 + 4);
    union { unsigned short us[8]; bf16x8 v; } u0, u1;
    u0.us[0]=f2bf(-2.f*a.x); u0.us[1]=f2bf(-2.f*a.y); u0.us[2]=f2bf(-2.f*a.z); u0.us[3]=f2bf(-2.f*a.w);
    u0.us[4]=f2bf(-2.f*b.x); u0.us[5]=f2bf(-2.f*b.y); u0.us[6]=f2bf(-2.f*b.z); u0.us[7]=f2bf(-2.f*b.w);
    u1.us[0]=f2bf(-2.f*c.x); u1.us[1]=f2bf(-2.f*c.y); u1.us[2]=f2bf(-2.f*c.z); u1.us[3]=f2bf(-2.f*c.w);
    u1.us[4]=f2bf(-2.f*d.x); u1.us[5]=f2bf(-2.f*d.y); u1.us[6]=f2bf(-2.f*d.z); u1.us[7]=f2bf(-2.f*d.w);
    xb0[s] = u0.v; xb1[s] = u1.v;
  }

  if (t < 128) rowcnt[t] = 0;

  float smin0 = FLT_MAX, smin1 = FLT_MAX;
  const unsigned char* srcbase = kbf + ((size_t)(split * NCHUNK) << 14);
  const size_t pb0 = ((size_t)xrow0 * NSPLIT + split) * (size_t)CAP;
  const size_t pb1 = ((size_t)xrow1 * NSPLIT + split) * (size_t)CAP;

  auto STAGE = [&](int c, int buf) { // linear 16KB, 2 x 16B per thread
    const unsigned char* src = srcbase + ((size_t)c << 14);
#pragma unroll
    for (int i = 0; i < 2; ++i)
      gl_lds16(src + (((i * 512) + t) << 4),
               (unsigned char*)tiles[buf] + ((i * 512 + wv * 64) << 4));
  };
  auto LOADQ = [&](int c) {
    return *(const float4*)(ksqg + sb + c * CHUNK_KEYS + mw * 16 + hi * 4);
  };

  f32x4 a0, a1;
  float4 kqc, kqn;

  auto COMPUTE = [&](int buf) { // acc init = ksq (fold), then MFMA
    const unsigned char* tile = tiles[buf];
    f32x4 ini;
    ini[0] = kqc.x; ini[1] = kqc.y; ini[2] = kqc.z; ini[3] = kqc.w;
    a0 = ini; a1 = ini;
    __builtin_amdgcn_s_setprio(1);
#pragma unroll
    for (int s = 0; s < 8; ++s) {
      const unsigned char* rp = tile + (s * 4 + hi) * 512 + (mw * 16 + lo4) * 16;
      bf16x8 af = *(const bf16x8*)rp;
      a0 = __builtin_amdgcn_mfma_f32_16x16x32_bf16(af, xb0[s], a0, 0, 0, 0);
      a1 = __builtin_amdgcn_mfma_f32_16x16x32_bf16(af, xb1[s], a1, 0, 0, 0);
    }
    __builtin_amdgcn_s_setprio(0);
  };

  auto SEL = [&](int c, bool append, float tau0, float tau1) {
    float mb0 = fminf(fminf(a0[0], a0[1]), fminf(a0[2], a0[3]));
    float mb1 = fminf(fminf(a1[0], a1[1]), fminf(a1[2], a1[3]));
    smin0 = fminf(smin0, mb0);
    smin1 = fminf(smin1, mb1);
    if (append) {
      const int kloc = c * CHUNK_KEYS + mw * 16 + hi * 4; // 12-bit local idx
      if (mb0 <= tau0) { // rare
#pragma unroll
        for (int i = 0; i < 4; ++i) {
          if (a0[i] <= tau0) {
            unsigned slot = atomicAdd(&rowcnt[rl0], 1u);
            if ((int)slot < CAP)
              pools[pb0 + slot] = (ford(a0[i]) & 0xFFFFF000u) | (unsigned)(kloc + i);
          }
        }
      }
      if (mb1 <= tau1) {
#pragma unroll
        for (int i = 0; i < 4; ++i) {
          if (a1[i] <= tau1) {
            unsigned slot = atomicAdd(&rowcnt[rl1], 1u);
            if ((int)slot < CAP)
              pools[pb1 + slot] = (ford(a1[i]) & 0xFFFFF000u) | (unsigned)(kloc + i);
          }
        }
      }
    }
  };

  auto RDTAU = [&](float& tau0, float& tau1) { // max over both mw entries
    tau0 = fmaxf(tauh[0][ws][lo4][0], tauh[0][ws][lo4][1]);
    tau1 = fmaxf(tauh[1][ws][lo4][0], tauh[1][ws][lo4][1]);
  };

  auto PUBLISH = [&]() { // per wave: max over its 4 hi-stream minima
    float p0 = fmaxf(smin0, __shfl_xor(smin0, 16, 64));
    p0 = fmaxf(p0, __shfl_xor(p0, 32, 64));
    float p1 = fmaxf(smin1, __shfl_xor(smin1, 16, 64));
    p1 = fmaxf(p1, __shfl_xor(p1, 32, 64));
    if (hi == 0) {
      tauh[0][ws][lo4][mw] = p0;
      tauh[1][ws][lo4][mw] = p1;
    }
  };

  // ---- prologue: tau from chunks 0 and 64 (minima only), then prime ring
  STAGE(0, 0);
  STAGE(64, 1);
  __syncthreads();               // full drain (prologue only)
  kqc = LOADQ(0);
  COMPUTE(0); SEL(0, false, 0.f, 0.f);
  kqc = LOADQ(64);
  COMPUTE(1); SEL(64, false, 0.f, 0.f);
  PUBLISH();
  __syncthreads();               // tauh visible; prologue reads done
  STAGE(1, 1);                   // chunk 0 still valid in buf 0
  STAGE(2, 2);
  kqc = LOADQ(0);
  kqn = LOADQ(1);

#pragma unroll 1
  for (int c = 0; c < NCHUNK; ++c) {
    asm volatile("s_waitcnt vmcnt(4)" ::: "memory"); // chunk c landed; c+1,c+2 in flight
    __builtin_amdgcn_s_barrier();
    float tau0, tau1;
    RDTAU(tau0, tau1);           // lagged/racy tau: always a valid upper bound
    COMPUTE(c & 3);
    SEL(c, true, tau0, tau1);
    if (c & 1) PUBLISH();
    kqc = kqn;
    kqn = LOADQ((c + 2 < NCHUNK) ? c + 2 : 0);
    const int cs = (c + 3 < NCHUNK) ? c + 3 : c + 3 - NCHUNK; // wrap: dummy
    STAGE(cs, (c + 3) & 3);
  }

  __syncthreads();
  if (t < 128) counts[(size_t)(rb + t) * NSPLIT + split] = rowcnt[t];
}

// ---------------------------------------------------------------------------
// knn_refine: per row (1 wave): scan the row's 16 pools (overflowed split ->
// exact fp32 rescan of THAT 4096-key split), tournament top-24 by quantized
// score, fp64-exact recompute, true top-8 (idx tiebreak), average values.
// ---------------------------------------------------------------------------
__global__ __launch_bounds__(64) void knn_refine(
    const float* __restrict__ x,
    const float* __restrict__ keys,
    const float* __restrict__ ksq,
    const float* __restrict__ values,
    const unsigned int* __restrict__ pools,
    const unsigned int* __restrict__ counts,
    int CAP,
    float* __restrict__ out) {
  __shared__ float4 xl[64];
  const int row = blockIdx.x;
  const int lane = threadIdx.x;

  xl[lane] = ((const float4*)(x + (size_t)row * DDIM))[lane];
  __syncthreads();

  unsigned long long h[8];
#pragma unroll
  for (int i = 0; i < 8; ++i) h[i] = ~0ULL;

  auto insert = [&](unsigned long long v) {
    if (v < h[7]) {
#pragma unroll
      for (int j = 7; j >= 1; --j) {
        unsigned long long a = h[j - 1];
        unsigned long long mx = a > v ? a : v;
        h[j] = (v < h[j]) ? mx : h[j];
      }
      h[0] = h[0] < v ? h[0] : v;
    }
  };

  for (int s = 0; s < NSPLIT; ++s) {
    unsigned cnt = counts[(size_t)row * NSPLIT + s];
    if ((int)cnt <= CAP) {
      const unsigned int* pp = pools + ((size_t)row * NSPLIT + s) * (size_t)CAP;
      for (int i = lane; i < (int)cnt; i += 64) {
        unsigned p = pp[i];
        unsigned gk = (unsigned)(s * SPLIT_KEYS) + (p & 0xFFFu);
        insert(((unsigned long long)(p & 0xFFFFF000u) << 16) | gk);
      }
    } else {
      // overflow fallback: exact fp32 rescan of this 4096-key split
      for (int kk = lane; kk < SPLIT_KEYS; kk += 64) {
        int gk = s * SPLIT_KEYS + kk;
        const float4* kr = (const float4*)(keys + (size_t)gk * DDIM);
        float acc = 0.f;
#pragma unroll 8
        for (int d = 0; d < 64; ++d) {
          float4 kv = kr[d], xv = xl[d];
          acc = fmaf(kv.x, xv.x, acc); acc = fmaf(kv.y, xv.y, acc);
          acc = fmaf(kv.z, xv.z, acc); acc = fmaf(kv.w, xv.w, acc);
        }
        float sc = fmaf(-2.0f, acc, ksq[gk]);
        insert(((unsigned long long)(ford(sc) & 0xFFFFF000u) << 16) | (unsigned)gk);
      }
    }
  }

  // ---- tournament: top-24 by quantized score (u64 unique: gk in low 16b)
  int myidx = 0;
#pragma unroll 1
  for (int r = 0; r < 24; ++r) {
    unsigned long long m = h[0];
#pragma unroll
    for (int off = 32; off; off >>= 1) {
      unsigned long long o = shfl_xor_u64(m, off);
      m = o < m ? o : m;
    }
    if (lane == r) myidx = (int)(m & 0xFFFFu);
    if (h[0] == m) {
#pragma unroll
      for (int i = 0; i < 7; ++i) h[i] = h[i + 1];
      h[7] = ~0ULL;
    }
  }

  // ---- exact fp64 distance for my candidate
  double dv = 1e300;
  if (lane < 24) {
    const float4* kr = (const float4*)(keys + (size_t)myidx * DDIM);
    double s = 0.0;
#pragma unroll 8
    for (int d = 0; d < 64; ++d) {
      float4 kv = kr[d], xv = xl[d];
      double d0 = (double)xv.x - (double)kv.x;
      double d1 = (double)xv.y - (double)kv.y;
      double d2 = (double)xv.z - (double)kv.z;
      double d3 = (double)xv.w - (double)kv.w;
      s += d0 * d0 + d1 * d1 + d2 * d2 + d3 * d3;
    }
    dv = s;
  }

  int di = myidx;
  int chosen[8];
#pragma unroll
  for (int r = 0; r < 8; ++r) {
    double m = dv; int mi = di;
#pragma unroll
    for (int off = 32; off; off >>= 1) {
      double om = shfl_xor_f64(m, off);
      int omi = __shfl_xor(mi, off, 64);
      if (om < m || (om == m && omi < mi)) { m = om; mi = omi; }
    }
    chosen[r] = mi;
    if (di == mi && dv < 1e300) dv = 1e300;
  }

  if (lane < NCH) {
    double a = 0.0;
#pragma unroll
    for (int r = 0; r < 8; ++r) a += (double)values[(size_t)chosen[r] * NCH + lane];
    out[row * NCH + lane] = (float)(a * 0.125);
  }
}

// ---------------------------------------------------------------------------
extern "C" void kernel_launch(void* const* d_in, const int* in_sizes, int n_in,
                              void* d_out, int out_size, void* d_ws, size_t ws_size,
                              hipStream_t stream) {
  (void)in_sizes; (void)n_in; (void)out_size;
  const float* x      = (const float*)d_in[0];
  const float* keys   = (const float*)d_in[1];
  const float* values = (const float*)d_in[2];
  float* out = (float*)d_out;

  char* ws = (char*)d_ws;
  unsigned char* kbf = (unsigned char*)ws;                            // 32 MB transposed bf16 keys
  float* ksq   = (float*)(ws + 33554432);                             // 256 KB
  unsigned int* counts = (unsigned int*)(ws + 33554432 + 262144);     // 256 KB (4096x16)
  unsigned int* pools  = (unsigned int*)(ws + 33554432 + 262144 + 262144);

  size_t base = 33554432 + 262144 + 262144;
  size_t cap = (ws_size > base) ? (ws_size - base) / ((size_t)B_ROWS * NSPLIT * 4) : 60;
  if (cap < 60) cap = 60;      // 60 -> pool ends <49.8 MB (< proven 50.6)
  if (cap > 512) cap = 512;
  int CAP = (int)cap;

  transpose_keys<<<N_KEYS / 128, 256, 0, stream>>>(keys, kbf, ksq);
  knn_main<<<(B_ROWS / ROWS_PER_BLK) * NSPLIT, 512, 0, stream>>>(
      x, kbf, ksq, pools, counts, CAP);
  knn_refine<<<B_ROWS, 64, 0, stream>>>(x, keys, ksq, values, pools, counts, CAP, out);
}